// Round 1
// baseline (666.537 us; speedup 1.0000x reference)
//
#include <hip/hip_runtime.h>

#define BB 32
#define CC 768
#define SS 1024
#define LLn 77
#define DD 512
#define LP 80      // padded L
#define ITILE 16
#define JCH 48
#define TS_STRIDE 88   // halves, phase-2 t chunk stride (bank-conflict-free for b64 reads)
#define TT_STRIDE 52   // halves, phase-4 transposed t stride
#define SC_STRIDE 776  // f32, logits row stride (768+8 to spread banks)

#define RATIO 0.0751953125f   // 77/1024 exact in fp32
#define IRATIO 13.298701f     // ~1024/77 (only used for conservative loop bounds)

__device__ __forceinline__ float bf2f(unsigned int h16) {
    unsigned int u = h16 << 16;
    float f; __builtin_memcpy(&f, &u, 4); return f;
}
__device__ __forceinline__ unsigned short f2bf(float f) {
    unsigned int u; __builtin_memcpy(&u, &f, 4);
    u += 0x7fffu + ((u >> 16) & 1u);   // RNE
    return (unsigned short)(u >> 16);
}

// K1: t[b,l,c] = sum_d text[b,l,d] * W[d,c]
__global__ __launch_bounds__(256) void k_tgemm(const float* __restrict__ text,
                                               const float* __restrict__ Wt,
                                               float* __restrict__ t_ws) {
    __shared__ float txt_s[7 * 512];
    const int b = blockIdx.y;
    const int l0 = blockIdx.x * 7;     // 11 groups * 7 = 77
    const int tid = threadIdx.x;
    for (int i4 = tid; i4 < 7 * 128; i4 += 256) {
        int r = i4 >> 7, col = (i4 & 127) << 2;
        *reinterpret_cast<float4*>(&txt_s[r * 512 + col]) =
            *reinterpret_cast<const float4*>(&text[(b * LLn + l0 + r) * DD + col]);
    }
    __syncthreads();
    float acc[7][3];
#pragma unroll
    for (int r = 0; r < 7; ++r) { acc[r][0] = 0.f; acc[r][1] = 0.f; acc[r][2] = 0.f; }
    const float* wp = Wt + tid;
#pragma unroll 4
    for (int d = 0; d < DD; ++d) {
        float w0 = wp[d * CC];
        float w1 = wp[d * CC + 256];
        float w2 = wp[d * CC + 512];
#pragma unroll
        for (int r = 0; r < 7; ++r) {
            float tv = txt_s[r * 512 + d];
            acc[r][0] = fmaf(tv, w0, acc[r][0]);
            acc[r][1] = fmaf(tv, w1, acc[r][1]);
            acc[r][2] = fmaf(tv, w2, acc[r][2]);
        }
    }
#pragma unroll
    for (int r = 0; r < 7; ++r) {
        float* op = &t_ws[(b * LLn + l0 + r) * CC];
        op[tid] = acc[r][0]; op[tid + 256] = acc[r][1]; op[tid + 512] = acc[r][2];
    }
}

// K2: qh[b,c,l] = sum_s A[s,l] * q[b,c,s]  (interp folded into q)
__global__ __launch_bounds__(256) void k_qh(const float* __restrict__ q,
                                            float* __restrict__ qh_ws) {
    __shared__ float qs[3 * 1024];
    const int b = blockIdx.y;
    const int c0 = blockIdx.x * 3;     // 256 * 3 = 768
    const int tid = threadIdx.x;
    for (int i4 = tid; i4 < 3 * 256; i4 += 256) {
        int r = i4 >> 8, col = (i4 & 255) << 2;
        *reinterpret_cast<float4*>(&qs[r * 1024 + col]) =
            *reinterpret_cast<const float4*>(&q[(b * CC + c0 + r) * SS + col]);
    }
    __syncthreads();
    const int r = tid / LP, l = tid % LP;
    if (r < 3 && l < LLn) {
        int s_lo = max(0, (int)floorf(((float)l - 0.5f) * IRATIO - 0.5f) - 1);
        int s_hi = min(SS - 1, (int)ceilf(((float)l + 1.5f) * IRATIO - 0.5f) + 1);
        float acc = 0.f;
        for (int s = s_lo; s <= s_hi; ++s) {
            float src = fmaf((float)s + 0.5f, RATIO, -0.5f);
            src = fminf(fmaxf(src, 0.f), 76.f);
            int i0 = (int)src;
            float w = src - (float)i0;
            int i1 = (i0 < 76) ? i0 + 1 : 76;
            float qv = qs[r * 1024 + s];
            if (i0 == l) acc = fmaf(1.f - w, qv, acc);
            if (i1 == l) acc = fmaf(w, qv, acc);
        }
        qh_ws[(b * CC + c0 + r) * LP + l] = acc;
    }
}

// K3: fused  logits = qh . t^T  -> softmax -> u = attn . t   per (b, 16-row tile)
__global__ __launch_bounds__(256) void k_attn(const float* __restrict__ qh_ws,
                                              const float* __restrict__ t_ws,
                                              float* __restrict__ u_ws) {
    __shared__ float qh_s[ITILE * LP];                 // 5120 B
    __shared__ float sc[ITILE * SC_STRIDE];            // 49664 B
    __shared__ unsigned short ts[JCH * TS_STRIDE];     // 8448 B (aliased as tt[80*52])
    const int b = blockIdx.y;
    const int iBase = blockIdx.x * ITILE;
    const int tid = threadIdx.x;
    const int i = tid >> 4;       // row within tile
    const int jq = tid & 15;

    for (int idx = tid; idx < ITILE * LP; idx += 256) {
        int ii = idx / LP, l = idx % LP;
        qh_s[idx] = (l < LLn) ? qh_ws[(b * CC + iBase + ii) * LP + l] : 0.f;
    }

    // -------- phase 2: logits --------
    const float scale = 0.03125f;  // 1024^-0.5
    for (int ch = 0; ch < CC / JCH; ++ch) {
        const int j0 = ch * JCH;
        __syncthreads();
        for (int idx = tid; idx < JCH * LP; idx += 256) {
            int l = idx / JCH, jj = idx % JCH;
            float v = (l < LLn) ? t_ws[(b * LLn + l) * CC + j0 + jj] : 0.f;
            ts[jj * TS_STRIDE + l] = f2bf(v);
        }
        __syncthreads();
        float acc[3] = {0.f, 0.f, 0.f};
        for (int l = 0; l < LP; l += 4) {
            float4 qa = *reinterpret_cast<const float4*>(&qh_s[i * LP + l]);
#pragma unroll
            for (int k = 0; k < 3; ++k) {
                int r = jq + (k << 4);
                uint2 hv = *reinterpret_cast<const uint2*>(&ts[r * TS_STRIDE + l]);
                acc[k] = fmaf(bf2f(hv.x & 0xffffu), qa.x, acc[k]);
                acc[k] = fmaf(bf2f(hv.x >> 16),     qa.y, acc[k]);
                acc[k] = fmaf(bf2f(hv.y & 0xffffu), qa.z, acc[k]);
                acc[k] = fmaf(bf2f(hv.y >> 16),     qa.w, acc[k]);
            }
        }
#pragma unroll
        for (int k = 0; k < 3; ++k)
            sc[i * SC_STRIDE + j0 + jq + (k << 4)] = acc[k] * scale;
    }
    __syncthreads();

    // -------- softmax over each row (16 lanes per row) --------
    float m = -1e30f;
    for (int k = 0; k < CC / 16; ++k)
        m = fmaxf(m, sc[i * SC_STRIDE + jq + (k << 4)]);
#pragma unroll
    for (int off = 8; off >= 1; off >>= 1) m = fmaxf(m, __shfl_xor(m, off));
    float ssum = 0.f;
    for (int k = 0; k < CC / 16; ++k) {
        float e = __expf(sc[i * SC_STRIDE + jq + (k << 4)] - m);
        sc[i * SC_STRIDE + jq + (k << 4)] = e;
        ssum += e;
    }
#pragma unroll
    for (int off = 8; off >= 1; off >>= 1) ssum += __shfl_xor(ssum, off);
    const float inv = 1.f / ssum;   // folded into the u write (u linear in attn)

    // -------- phase 4: u = attn . t --------
    float pacc[5] = {0.f, 0.f, 0.f, 0.f, 0.f};
    unsigned short* tt = ts;  // reuse buffer, [80][TT_STRIDE]
    for (int ch = 0; ch < CC / JCH; ++ch) {
        const int j0 = ch * JCH;
        __syncthreads();
        for (int idx = tid; idx < JCH * LP; idx += 256) {
            int l = idx / JCH, jj = idx % JCH;
            float v = (l < LLn) ? t_ws[(b * LLn + l) * CC + j0 + jj] : 0.f;
            tt[l * TT_STRIDE + jj] = f2bf(v);
        }
        __syncthreads();
        for (int jj = 0; jj < JCH; jj += 4) {
            float4 sv = *reinterpret_cast<const float4*>(&sc[i * SC_STRIDE + j0 + jj]);
#pragma unroll
            for (int k = 0; k < 5; ++k) {
                int l = jq + (k << 4);
                uint2 hv = *reinterpret_cast<const uint2*>(&tt[l * TT_STRIDE + jj]);
                pacc[k] = fmaf(bf2f(hv.x & 0xffffu), sv.x, pacc[k]);
                pacc[k] = fmaf(bf2f(hv.x >> 16),     sv.y, pacc[k]);
                pacc[k] = fmaf(bf2f(hv.y & 0xffffu), sv.z, pacc[k]);
                pacc[k] = fmaf(bf2f(hv.y >> 16),     sv.w, pacc[k]);
            }
        }
    }
#pragma unroll
    for (int k = 0; k < 5; ++k) {
        int l = jq + (k << 4);
        if (l < LLn) u_ws[(b * CC + iBase + i) * LP + l] = pacc[k] * inv;
    }
}

// K4: out = q + gamma * interp(u)
__global__ __launch_bounds__(256) void k_out(const float* __restrict__ q,
                                             const float* __restrict__ u_ws,
                                             const float* __restrict__ gamma,
                                             float* __restrict__ out) {
    __shared__ float us[LP];
    const int b = blockIdx.y;
    const int c = blockIdx.x;
    const int tid = threadIdx.x;
    if (tid < LLn) us[tid] = u_ws[(b * CC + c) * LP + tid];
    __syncthreads();
    const float g = gamma[0];
    const int base = (b * CC + c) * SS + tid * 4;
    float4 qv = *reinterpret_cast<const float4*>(&q[base]);
    float rr[4];
    const float* qp = reinterpret_cast<const float*>(&qv);
#pragma unroll
    for (int k = 0; k < 4; ++k) {
        int s = tid * 4 + k;
        float src = fmaf((float)s + 0.5f, RATIO, -0.5f);
        src = fminf(fmaxf(src, 0.f), 76.f);
        int i0 = (int)src;
        float w = src - (float)i0;
        int i1 = (i0 < 76) ? i0 + 1 : 76;
        float uv = fmaf(1.f - w, us[i0], w * us[i1]);
        rr[k] = qp[k] + g * uv;
    }
    *reinterpret_cast<float4*>(&out[base]) = make_float4(rr[0], rr[1], rr[2], rr[3]);
}

extern "C" void kernel_launch(void* const* d_in, const int* in_sizes, int n_in,
                              void* d_out, int out_size, void* d_ws, size_t ws_size,
                              hipStream_t stream) {
    const float* img   = (const float*)d_in[0];
    const float* text  = (const float*)d_in[1];
    const float* Wt    = (const float*)d_in[2];
    const float* gamma = (const float*)d_in[3];
    float* out = (float*)d_out;
    char* ws = (char*)d_ws;
    float* t_ws  = (float*)(ws);                 // 32*77*768*4  = 7,569,408 B
    float* qh_ws = (float*)(ws + 7569408);       // 32*768*80*4  = 7,864,320 B
    float* u_ws  = (float*)(ws + 15433728);      // 32*768*80*4  = 7,864,320 B

    k_tgemm<<<dim3(11, BB), 256, 0, stream>>>(text, Wt, t_ws);
    k_qh  <<<dim3(256, BB), 256, 0, stream>>>(img, qh_ws);
    k_attn<<<dim3(CC / ITILE, BB), 256, 0, stream>>>(qh_ws, t_ws, u_ws);
    k_out <<<dim3(CC, BB), 256, 0, stream>>>(img, u_ws, gamma, out);
}

// Round 2
// 203.713 us; speedup vs baseline: 3.2719x; 3.2719x over previous
//
#include <hip/hip_runtime.h>

#define BB 32
#define CC 768
#define SS 1024
#define LLn 77
#define DD 512
#define LP 80      // padded L for f32 u buffer / tlc rows
#define LP2 96     // padded L (K dim) for bf16 MFMA operands, mult of 32

#define RATIO 0.0751953125f   // 77/1024 exact in fp32
#define IRATIO 13.298701f     // ~1024/77 (only used for conservative loop bounds)

typedef short bf16x8 __attribute__((ext_vector_type(8)));
typedef float f32x4 __attribute__((ext_vector_type(4)));
typedef unsigned short u16;

__device__ __forceinline__ float bf2f(unsigned int h16) {
    unsigned int u = h16 << 16;
    float f; __builtin_memcpy(&f, &u, 4); return f;
}
__device__ __forceinline__ u16 f2bf(float f) {
    unsigned int u; __builtin_memcpy(&u, &f, 4);
    u += 0x7fffu + ((u >> 16) & 1u);   // RNE
    return (u16)(u >> 16);
}

// K1: t[b,l,c] = sum_d text[b,l,d] * W[d,c]; emit bf16 in two layouts:
//   tc[b, c, 96]  (logits B operand: B[k=l, n=c])
//   tlc[b, l(80), 768] (PV B operand: B[k=c, n=l])
__global__ __launch_bounds__(256) void k_tgemm(const float* __restrict__ text,
                                               const float* __restrict__ Wt,
                                               u16* __restrict__ tc,
                                               u16* __restrict__ tlc) {
    __shared__ float txt_s[7 * 512];
    const int b = blockIdx.y;
    const int l0 = blockIdx.x * 7;     // 11 groups * 7 = 77
    const int tid = threadIdx.x;
    for (int i4 = tid; i4 < 7 * 128; i4 += 256) {
        int r = i4 >> 7, col = (i4 & 127) << 2;
        *reinterpret_cast<float4*>(&txt_s[r * 512 + col]) =
            *reinterpret_cast<const float4*>(&text[(b * LLn + l0 + r) * DD + col]);
    }
    __syncthreads();
    float acc[7][3];
#pragma unroll
    for (int r = 0; r < 7; ++r) { acc[r][0] = 0.f; acc[r][1] = 0.f; acc[r][2] = 0.f; }
    const float* wp = Wt + tid;
#pragma unroll 4
    for (int d = 0; d < DD; ++d) {
        float w0 = wp[d * CC];
        float w1 = wp[d * CC + 256];
        float w2 = wp[d * CC + 512];
#pragma unroll
        for (int r = 0; r < 7; ++r) {
            float tv = txt_s[r * 512 + d];
            acc[r][0] = fmaf(tv, w0, acc[r][0]);
            acc[r][1] = fmaf(tv, w1, acc[r][1]);
            acc[r][2] = fmaf(tv, w2, acc[r][2]);
        }
    }
#pragma unroll
    for (int r = 0; r < 7; ++r) {
        int l = l0 + r;
#pragma unroll
        for (int k = 0; k < 3; ++k) {
            int c = tid + (k << 8);
            u16 v = f2bf(acc[r][k]);
            tc[((size_t)b * CC + c) * LP2 + l] = v;
            tlc[((size_t)b * LP + l) * CC + c] = v;
        }
    }
    if (blockIdx.x == 10) {   // zero the K/N padding once per b
#pragma unroll
        for (int k = 0; k < 3; ++k) {
            int c = tid + (k << 8);
            for (int l = LLn; l < LP2; ++l) tc[((size_t)b * CC + c) * LP2 + l] = 0;
            for (int l = LLn; l < LP;  ++l) tlc[((size_t)b * LP + l) * CC + c] = 0;
        }
    }
}

// K2: qh[b,c,l] = (sum_s A[s,l] * q[b,c,s]) * S^-0.5, bf16, [b, c, 96] (logits A operand)
__global__ __launch_bounds__(256) void k_qh(const float* __restrict__ q,
                                            u16* __restrict__ qh) {
    __shared__ float qs[3 * 1024];
    const int b = blockIdx.y;
    const int c0 = blockIdx.x * 3;     // 256 * 3 = 768
    const int tid = threadIdx.x;
    for (int i4 = tid; i4 < 3 * 256; i4 += 256) {
        int r = i4 >> 8, col = (i4 & 255) << 2;
        *reinterpret_cast<float4*>(&qs[r * 1024 + col]) =
            *reinterpret_cast<const float4*>(&q[(b * CC + c0 + r) * SS + col]);
    }
    __syncthreads();
    for (int idx = tid; idx < 3 * LP2; idx += 256) {
        int r = idx / LP2, l = idx % LP2;
        float val = 0.f;
        if (l < LLn) {
            int s_lo = max(0, (int)floorf(((float)l - 0.5f) * IRATIO - 0.5f) - 1);
            int s_hi = min(SS - 1, (int)ceilf(((float)l + 1.5f) * IRATIO - 0.5f) + 1);
            float a = 0.f;
            for (int s = s_lo; s <= s_hi; ++s) {
                float src = fmaf((float)s + 0.5f, RATIO, -0.5f);
                src = fminf(fmaxf(src, 0.f), 76.f);
                int i0 = (int)src;
                float w = src - (float)i0;
                int i1 = (i0 < 76) ? i0 + 1 : 76;
                float qv = qs[r * 1024 + s];
                if (i0 == l) a = fmaf(1.f - w, qv, a);
                if (i1 == l) a = fmaf(w, qv, a);
            }
            val = a * 0.03125f;   // fold 1024^-0.5 into qh
        }
        qh[((size_t)b * CC + c0 + r) * LP2 + l] = f2bf(val);
    }
}

// K3: MFMA fused attention: logits(16x768) -> softmax -> u = attn . t (16x80)
// 4 waves/block; all waves share the 16 rows, each wave owns a 192-col j-slice.
__global__ __launch_bounds__(256, 2) void k_attn(const u16* __restrict__ qh,
                                                 const u16* __restrict__ tc,
                                                 const u16* __restrict__ tlc,
                                                 float* __restrict__ u_ws) {
    __shared__ float pmax[4][16];
    __shared__ float psum[4][16];
    __shared__ float invl[16];
    __shared__ __align__(16) char pbuf[4][6400];   // per-wave: P bf16 [16][200] / u f32 [16][81]

    const int b = blockIdx.y;
    const int iBase = blockIdx.x * 16;
    const int tid = threadIdx.x;
    const int w = tid >> 6, lane = tid & 63;
    const int lm = lane & 15, lg = lane >> 4;

    // ---- logits: A = qh rows (3 k-steps), B = tc rows of this wave's j-slice ----
    const u16* qbase = qh + ((size_t)b * CC + iBase + lm) * LP2 + lg * 8;
    bf16x8 aq0 = *reinterpret_cast<const bf16x8*>(qbase);
    bf16x8 aq1 = *reinterpret_cast<const bf16x8*>(qbase + 32);
    bf16x8 aq2 = *reinterpret_cast<const bf16x8*>(qbase + 64);

    f32x4 acc[12];
#pragma unroll
    for (int t = 0; t < 12; ++t) acc[t] = (f32x4){0.f, 0.f, 0.f, 0.f};

    const u16* tcb = tc + ((size_t)b * CC + w * 192 + lm) * LP2 + lg * 8;
#pragma unroll
    for (int t = 0; t < 12; ++t) {
        const u16* p = tcb + (size_t)t * 16 * LP2;
        bf16x8 b0 = *reinterpret_cast<const bf16x8*>(p);
        bf16x8 b1 = *reinterpret_cast<const bf16x8*>(p + 32);
        bf16x8 b2 = *reinterpret_cast<const bf16x8*>(p + 64);
        acc[t] = __builtin_amdgcn_mfma_f32_16x16x32_bf16(aq0, b0, acc[t], 0, 0, 0);
        acc[t] = __builtin_amdgcn_mfma_f32_16x16x32_bf16(aq1, b1, acc[t], 0, 0, 0);
        acc[t] = __builtin_amdgcn_mfma_f32_16x16x32_bf16(aq2, b2, acc[t], 0, 0, 0);
    }

    // ---- softmax (C layout: col = lane&15, row = lg*4 + reg) ----
    float m[4];
#pragma unroll
    for (int r = 0; r < 4; ++r) {
        float mm = acc[0][r];
#pragma unroll
        for (int t = 1; t < 12; ++t) mm = fmaxf(mm, acc[t][r]);
#pragma unroll
        for (int off = 8; off >= 1; off >>= 1) mm = fmaxf(mm, __shfl_xor(mm, off));
        m[r] = mm;
    }
    if (lm == 0) {
#pragma unroll
        for (int r = 0; r < 4; ++r) pmax[w][lg * 4 + r] = m[r];
    }
    __syncthreads();
    float gm[4];
#pragma unroll
    for (int r = 0; r < 4; ++r) {
        int row = lg * 4 + r;
        gm[r] = fmaxf(fmaxf(pmax[0][row], pmax[1][row]), fmaxf(pmax[2][row], pmax[3][row]));
    }
    float s[4] = {0.f, 0.f, 0.f, 0.f};
#pragma unroll
    for (int t = 0; t < 12; ++t) {
#pragma unroll
        for (int r = 0; r < 4; ++r) {
            float e = __expf(acc[t][r] - gm[r]);
            acc[t][r] = e;
            s[r] += e;
        }
    }
#pragma unroll
    for (int r = 0; r < 4; ++r) {
#pragma unroll
        for (int off = 8; off >= 1; off >>= 1) s[r] += __shfl_xor(s[r], off);
    }
    if (lm == 0) {
#pragma unroll
        for (int r = 0; r < 4; ++r) psum[w][lg * 4 + r] = s[r];
    }
    __syncthreads();
    if (w == 0 && lm == 0) {
#pragma unroll
        for (int r = 0; r < 4; ++r) {
            int row = lg * 4 + r;
            invl[row] = 1.0f / (psum[0][row] + psum[1][row] + psum[2][row] + psum[3][row]);
        }
    }

    // ---- P -> bf16 into per-wave LDS (stride 200 halves: <=2-way banks) ----
    u16* P = (u16*)pbuf[w];
#pragma unroll
    for (int t = 0; t < 12; ++t) {
#pragma unroll
        for (int r = 0; r < 4; ++r)
            P[(lg * 4 + r) * 200 + t * 16 + lm] = f2bf(acc[t][r]);
    }

    // ---- PV: u[16 x 80] += P[16 x 192] . tlc[192 x 80] ----
    f32x4 u[5];
#pragma unroll
    for (int nt = 0; nt < 5; ++nt) u[nt] = (f32x4){0.f, 0.f, 0.f, 0.f};
    const u16* tb = tlc + ((size_t)b * LP + lm) * CC + w * 192 + lg * 8;
#pragma unroll
    for (int ks = 0; ks < 6; ++ks) {
        bf16x8 pa = *reinterpret_cast<const bf16x8*>(&P[lm * 200 + ks * 32 + lg * 8]);
#pragma unroll
        for (int nt = 0; nt < 5; ++nt) {
            bf16x8 bv = *reinterpret_cast<const bf16x8*>(tb + (size_t)nt * 16 * CC + ks * 32);
            u[nt] = __builtin_amdgcn_mfma_f32_16x16x32_bf16(pa, bv, u[nt], 0, 0, 0);
        }
    }

    // ---- cross-wave u reduce (alias P buffer; wave-local reuse is ordered) ----
    float* up = (float*)pbuf[w];
#pragma unroll
    for (int nt = 0; nt < 5; ++nt) {
#pragma unroll
        for (int r = 0; r < 4; ++r)
            up[(lg * 4 + r) * 81 + nt * 16 + lm] = u[nt][r];
    }
    __syncthreads();
#pragma unroll
    for (int k = 0; k < 5; ++k) {
        int idx = tid + (k << 8);
        int row = idx / LP, l = idx % LP;
        float v = ((float*)pbuf[0])[row * 81 + l] + ((float*)pbuf[1])[row * 81 + l]
                + ((float*)pbuf[2])[row * 81 + l] + ((float*)pbuf[3])[row * 81 + l];
        u_ws[((size_t)b * CC + iBase + row) * LP + l] = v * invl[row];
    }
}

// K4: out = q + gamma * interp(u)
__global__ __launch_bounds__(256) void k_out(const float* __restrict__ q,
                                             const float* __restrict__ u_ws,
                                             const float* __restrict__ gamma,
                                             float* __restrict__ out) {
    __shared__ float us[LP];
    const int b = blockIdx.y;
    const int c = blockIdx.x;
    const int tid = threadIdx.x;
    if (tid < LLn) us[tid] = u_ws[((size_t)b * CC + c) * LP + tid];
    __syncthreads();
    const float g = gamma[0];
    const int base = (b * CC + c) * SS + tid * 4;
    float4 qv = *reinterpret_cast<const float4*>(&q[base]);
    float rr[4];
    const float* qp = reinterpret_cast<const float*>(&qv);
#pragma unroll
    for (int k = 0; k < 4; ++k) {
        int s = tid * 4 + k;
        float src = fmaf((float)s + 0.5f, RATIO, -0.5f);
        src = fminf(fmaxf(src, 0.f), 76.f);
        int i0 = (int)src;
        float w = src - (float)i0;
        int i1 = (i0 < 76) ? i0 + 1 : 76;
        float uv = fmaf(1.f - w, us[i0], w * us[i1]);
        rr[k] = qp[k] + g * uv;
    }
    *reinterpret_cast<float4*>(&out[base]) = make_float4(rr[0], rr[1], rr[2], rr[3]);
}

extern "C" void kernel_launch(void* const* d_in, const int* in_sizes, int n_in,
                              void* d_out, int out_size, void* d_ws, size_t ws_size,
                              hipStream_t stream) {
    const float* img   = (const float*)d_in[0];
    const float* text  = (const float*)d_in[1];
    const float* Wt    = (const float*)d_in[2];
    const float* gamma = (const float*)d_in[3];
    float* out = (float*)d_out;
    char* ws = (char*)d_ws;
    u16*   tc_bf  = (u16*)(ws);                   // 32*768*96*2 = 4,718,592
    u16*   tlc_bf = (u16*)(ws + 4718592);         // 32*80*768*2 = 3,932,160
    u16*   qh_bf  = (u16*)(ws + 8650752);         // 32*768*96*2 = 4,718,592
    float* u_ws   = (float*)(ws + 13369344);      // 32*768*80*4 = 7,864,320

    k_tgemm<<<dim3(11, BB), 256, 0, stream>>>(text, Wt, tc_bf, tlc_bf);
    k_qh  <<<dim3(256, BB), 256, 0, stream>>>(img, qh_bf);
    k_attn<<<dim3(48, BB), 256, 0, stream>>>(qh_bf, tc_bf, tlc_bf, u_ws);
    k_out <<<dim3(CC, BB), 256, 0, stream>>>(img, u_ws, gamma, out);
}

// Round 3
// 150.220 us; speedup vs baseline: 4.4371x; 1.3561x over previous
//
#include <hip/hip_runtime.h>

#define BB 32
#define CC 768
#define SS 1024
#define LLn 77
#define DD 512
#define LP 80      // padded L for f32 u buffer / tlc rows
#define LP2 96     // padded L (K dim) for bf16 MFMA operands, mult of 32
#define MROWS 2464 // B * L = 32 * 77

#define RATIO 0.0751953125f   // 77/1024 exact in fp32
#define IRATIO 13.298701f     // ~1024/77 (only used for conservative loop bounds)

typedef short bf16x8 __attribute__((ext_vector_type(8)));
typedef float f32x4 __attribute__((ext_vector_type(4)));
typedef unsigned short u16;

__device__ __forceinline__ float bf2f(unsigned int h16) {
    unsigned int u = h16 << 16;
    float f; __builtin_memcpy(&f, &u, 4); return f;
}
__device__ __forceinline__ u16 f2bf(float f) {
    unsigned int u; __builtin_memcpy(&u, &f, 4);
    u += 0x7fffu + ((u >> 16) & 1u);   // RNE
    return (u16)(u >> 16);
}

// Convert text [B,L,D] f32 -> bf16 contiguous (A operand rows)
__global__ __launch_bounds__(256) void k_cvt_text(const float* __restrict__ text,
                                                  u16* __restrict__ At) {
    int i = blockIdx.x * 256 + threadIdx.x;   // float4 granularity
    if (i < MROWS * DD / 4) {
        float4 v = *reinterpret_cast<const float4*>(&text[(size_t)i * 4]);
        u16 o[4] = {f2bf(v.x), f2bf(v.y), f2bf(v.z), f2bf(v.w)};
        *reinterpret_cast<uint2*>(&At[(size_t)i * 4]) = *reinterpret_cast<uint2*>(o);
    }
}

// Convert + transpose W [D,C] f32 -> Wb [C,D] bf16 (B operand rows)
__global__ __launch_bounds__(256) void k_cvt_w(const float* __restrict__ Wt,
                                               u16* __restrict__ Wb) {
    __shared__ float tile[32][33];
    const int c0 = blockIdx.x * 32, d0 = blockIdx.y * 32;
    const int tx = threadIdx.x & 31, ty = threadIdx.x >> 5;  // ty 0..7
#pragma unroll
    for (int k = 0; k < 4; ++k) {
        int d = ty + k * 8;
        tile[d][tx] = Wt[(size_t)(d0 + d) * CC + c0 + tx];
    }
    __syncthreads();
#pragma unroll
    for (int k = 0; k < 4; ++k) {
        int c = ty + k * 8;
        Wb[(size_t)(c0 + c) * DD + d0 + tx] = f2bf(tile[tx][c]);
    }
}

// Zero the padding regions of tc ([77..95] per (b,c)) and tlc (l=77..79 rows)
__global__ __launch_bounds__(256) void k_pad(u16* __restrict__ tc, u16* __restrict__ tlc) {
    int idx = blockIdx.x * 256 + threadIdx.x;
    if (idx < BB * CC) {
        int b = idx / CC, c = idx % CC;
        u16* p = &tc[((size_t)b * CC + c) * LP2 + LLn];
#pragma unroll
        for (int k = 0; k < LP2 - LLn; ++k) p[k] = 0;
    }
    if (idx < BB * 3 * CC) {
        int b = idx / (3 * CC);
        int rem = idx - b * 3 * CC;
        int l = LLn + rem / CC;
        int c = rem % CC;
        tlc[((size_t)b * LP + l) * CC + c] = 0;
    }
}

// K1 (MFMA): t = text @ W  over flattened rows g = b*77+l.
// Grid (154, 4); 4 waves/block; wave owns 48 cols x 16 rows; K=512.
__global__ __launch_bounds__(256) void k_tgemm_mfma(const u16* __restrict__ At,
                                                    const u16* __restrict__ Wb,
                                                    u16* __restrict__ tc,
                                                    u16* __restrict__ tlc) {
    const int tid = threadIdx.x;
    const int w = tid >> 6, lane = tid & 63;
    const int lm = lane & 15, lg = lane >> 4;
    const int g0 = blockIdx.x * 16;
    const int c0 = blockIdx.y * 192 + w * 48;

    f32x4 acc[3];
#pragma unroll
    for (int nt = 0; nt < 3; ++nt) acc[nt] = (f32x4){0.f, 0.f, 0.f, 0.f};

    const u16* ap = At + (size_t)(g0 + lm) * DD + lg * 8;
    const u16* bp = Wb + (size_t)(c0 + lm) * DD + lg * 8;
#pragma unroll 4
    for (int ks = 0; ks < 16; ++ks) {
        bf16x8 aq = *reinterpret_cast<const bf16x8*>(ap + ks * 32);
#pragma unroll
        for (int nt = 0; nt < 3; ++nt) {
            bf16x8 bv = *reinterpret_cast<const bf16x8*>(bp + (size_t)nt * 16 * DD + ks * 32);
            acc[nt] = __builtin_amdgcn_mfma_f32_16x16x32_bf16(aq, bv, acc[nt], 0, 0, 0);
        }
    }
#pragma unroll
    for (int r = 0; r < 4; ++r) {
        int g = g0 + lg * 4 + r;
        int b = g / 77, l = g - b * 77;
#pragma unroll
        for (int nt = 0; nt < 3; ++nt) {
            int c = c0 + nt * 16 + lm;
            u16 v = f2bf(acc[nt][r]);
            tc[((size_t)b * CC + c) * LP2 + l] = v;
            tlc[((size_t)b * LP + l) * CC + c] = v;
        }
    }
}

// K2: qh[b,c,l] = (sum_s A[s,l] * q[b,c,s]) * S^-0.5, bf16, [b, c, 96] (logits A operand)
__global__ __launch_bounds__(256) void k_qh(const float* __restrict__ q,
                                            u16* __restrict__ qh) {
    __shared__ float qs[3 * 1024];
    const int b = blockIdx.y;
    const int c0 = blockIdx.x * 3;     // 256 * 3 = 768
    const int tid = threadIdx.x;
    for (int i4 = tid; i4 < 3 * 256; i4 += 256) {
        int r = i4 >> 8, col = (i4 & 255) << 2;
        *reinterpret_cast<float4*>(&qs[r * 1024 + col]) =
            *reinterpret_cast<const float4*>(&q[(b * CC + c0 + r) * SS + col]);
    }
    __syncthreads();
    for (int idx = tid; idx < 3 * LP2; idx += 256) {
        int r = idx / LP2, l = idx % LP2;
        float val = 0.f;
        if (l < LLn) {
            int s_lo = max(0, (int)floorf(((float)l - 0.5f) * IRATIO - 0.5f) - 1);
            int s_hi = min(SS - 1, (int)ceilf(((float)l + 1.5f) * IRATIO - 0.5f) + 1);
            float a = 0.f;
            for (int s = s_lo; s <= s_hi; ++s) {
                float src = fmaf((float)s + 0.5f, RATIO, -0.5f);
                src = fminf(fmaxf(src, 0.f), 76.f);
                int i0 = (int)src;
                float w = src - (float)i0;
                int i1 = (i0 < 76) ? i0 + 1 : 76;
                float qv = qs[r * 1024 + s];
                if (i0 == l) a = fmaf(1.f - w, qv, a);
                if (i1 == l) a = fmaf(w, qv, a);
            }
            val = a * 0.03125f;   // fold 1024^-0.5 into qh
        }
        qh[((size_t)b * CC + c0 + r) * LP2 + l] = f2bf(val);
    }
}

// K3: MFMA fused attention: logits(16x768) -> softmax -> u = attn . t (16x80)
// 4 waves/block; all waves share the 16 rows, each wave owns a 192-col j-slice.
__global__ __launch_bounds__(256, 2) void k_attn(const u16* __restrict__ qh,
                                                 const u16* __restrict__ tc,
                                                 const u16* __restrict__ tlc,
                                                 float* __restrict__ u_ws) {
    __shared__ float pmax[4][16];
    __shared__ float psum[4][16];
    __shared__ float invl[16];
    __shared__ __align__(16) char pbuf[4][6400];   // per-wave: P bf16 [16][200] / u f32 [16][81]

    const int b = blockIdx.y;
    const int iBase = blockIdx.x * 16;
    const int tid = threadIdx.x;
    const int w = tid >> 6, lane = tid & 63;
    const int lm = lane & 15, lg = lane >> 4;

    // ---- logits: A = qh rows (3 k-steps), B = tc rows of this wave's j-slice ----
    const u16* qbase = qh + ((size_t)b * CC + iBase + lm) * LP2 + lg * 8;
    bf16x8 aq0 = *reinterpret_cast<const bf16x8*>(qbase);
    bf16x8 aq1 = *reinterpret_cast<const bf16x8*>(qbase + 32);
    bf16x8 aq2 = *reinterpret_cast<const bf16x8*>(qbase + 64);

    f32x4 acc[12];
#pragma unroll
    for (int t = 0; t < 12; ++t) acc[t] = (f32x4){0.f, 0.f, 0.f, 0.f};

    const u16* tcb = tc + ((size_t)b * CC + w * 192 + lm) * LP2 + lg * 8;
#pragma unroll
    for (int t = 0; t < 12; ++t) {
        const u16* p = tcb + (size_t)t * 16 * LP2;
        bf16x8 b0 = *reinterpret_cast<const bf16x8*>(p);
        bf16x8 b1 = *reinterpret_cast<const bf16x8*>(p + 32);
        bf16x8 b2 = *reinterpret_cast<const bf16x8*>(p + 64);
        acc[t] = __builtin_amdgcn_mfma_f32_16x16x32_bf16(aq0, b0, acc[t], 0, 0, 0);
        acc[t] = __builtin_amdgcn_mfma_f32_16x16x32_bf16(aq1, b1, acc[t], 0, 0, 0);
        acc[t] = __builtin_amdgcn_mfma_f32_16x16x32_bf16(aq2, b2, acc[t], 0, 0, 0);
    }

    // ---- softmax (C layout: col = lane&15, row = lg*4 + reg) ----
    float m[4];
#pragma unroll
    for (int r = 0; r < 4; ++r) {
        float mm = acc[0][r];
#pragma unroll
        for (int t = 1; t < 12; ++t) mm = fmaxf(mm, acc[t][r]);
#pragma unroll
        for (int off = 8; off >= 1; off >>= 1) mm = fmaxf(mm, __shfl_xor(mm, off));
        m[r] = mm;
    }
    if (lm == 0) {
#pragma unroll
        for (int r = 0; r < 4; ++r) pmax[w][lg * 4 + r] = m[r];
    }
    __syncthreads();
    float gm[4];
#pragma unroll
    for (int r = 0; r < 4; ++r) {
        int row = lg * 4 + r;
        gm[r] = fmaxf(fmaxf(pmax[0][row], pmax[1][row]), fmaxf(pmax[2][row], pmax[3][row]));
    }
    float s[4] = {0.f, 0.f, 0.f, 0.f};
#pragma unroll
    for (int t = 0; t < 12; ++t) {
#pragma unroll
        for (int r = 0; r < 4; ++r) {
            float e = __expf(acc[t][r] - gm[r]);
            acc[t][r] = e;
            s[r] += e;
        }
    }
#pragma unroll
    for (int r = 0; r < 4; ++r) {
#pragma unroll
        for (int off = 8; off >= 1; off >>= 1) s[r] += __shfl_xor(s[r], off);
    }
    if (lm == 0) {
#pragma unroll
        for (int r = 0; r < 4; ++r) psum[w][lg * 4 + r] = s[r];
    }
    __syncthreads();
    if (w == 0 && lm == 0) {
#pragma unroll
        for (int r = 0; r < 4; ++r) {
            int row = lg * 4 + r;
            invl[row] = 1.0f / (psum[0][row] + psum[1][row] + psum[2][row] + psum[3][row]);
        }
    }

    // ---- P -> bf16 into per-wave LDS (stride 200 halves: <=2-way banks) ----
    u16* P = (u16*)pbuf[w];
#pragma unroll
    for (int t = 0; t < 12; ++t) {
#pragma unroll
        for (int r = 0; r < 4; ++r)
            P[(lg * 4 + r) * 200 + t * 16 + lm] = f2bf(acc[t][r]);
    }

    // ---- PV: u[16 x 80] += P[16 x 192] . tlc[192 x 80] ----
    f32x4 u[5];
#pragma unroll
    for (int nt = 0; nt < 5; ++nt) u[nt] = (f32x4){0.f, 0.f, 0.f, 0.f};
    const u16* tb = tlc + ((size_t)b * LP + lm) * CC + w * 192 + lg * 8;
#pragma unroll
    for (int ks = 0; ks < 6; ++ks) {
        bf16x8 pa = *reinterpret_cast<const bf16x8*>(&P[lm * 200 + ks * 32 + lg * 8]);
#pragma unroll
        for (int nt = 0; nt < 5; ++nt) {
            bf16x8 bv = *reinterpret_cast<const bf16x8*>(tb + (size_t)nt * 16 * CC + ks * 32);
            u[nt] = __builtin_amdgcn_mfma_f32_16x16x32_bf16(pa, bv, u[nt], 0, 0, 0);
        }
    }

    // ---- cross-wave u reduce (alias P buffer; wave-local reuse is ordered) ----
    float* up = (float*)pbuf[w];
#pragma unroll
    for (int nt = 0; nt < 5; ++nt) {
#pragma unroll
        for (int r = 0; r < 4; ++r)
            up[(lg * 4 + r) * 81 + nt * 16 + lm] = u[nt][r];
    }
    __syncthreads();
#pragma unroll
    for (int k = 0; k < 5; ++k) {
        int idx = tid + (k << 8);
        int row = idx / LP, l = idx % LP;
        float v = ((float*)pbuf[0])[row * 81 + l] + ((float*)pbuf[1])[row * 81 + l]
                + ((float*)pbuf[2])[row * 81 + l] + ((float*)pbuf[3])[row * 81 + l];
        u_ws[((size_t)b * CC + iBase + row) * LP + l] = v * invl[row];
    }
}

// K4: out = q + gamma * interp(u)
__global__ __launch_bounds__(256) void k_out(const float* __restrict__ q,
                                             const float* __restrict__ u_ws,
                                             const float* __restrict__ gamma,
                                             float* __restrict__ out) {
    __shared__ float us[LP];
    const int b = blockIdx.y;
    const int c = blockIdx.x;
    const int tid = threadIdx.x;
    if (tid < LLn) us[tid] = u_ws[((size_t)b * CC + c) * LP + tid];
    __syncthreads();
    const float g = gamma[0];
    const int base = (b * CC + c) * SS + tid * 4;
    float4 qv = *reinterpret_cast<const float4*>(&q[base]);
    float rr[4];
    const float* qp = reinterpret_cast<const float*>(&qv);
#pragma unroll
    for (int k = 0; k < 4; ++k) {
        int s = tid * 4 + k;
        float src = fmaf((float)s + 0.5f, RATIO, -0.5f);
        src = fminf(fmaxf(src, 0.f), 76.f);
        int i0 = (int)src;
        float w = src - (float)i0;
        int i1 = (i0 < 76) ? i0 + 1 : 76;
        float uv = fmaf(1.f - w, us[i0], w * us[i1]);
        rr[k] = qp[k] + g * uv;
    }
    *reinterpret_cast<float4*>(&out[base]) = make_float4(rr[0], rr[1], rr[2], rr[3]);
}

extern "C" void kernel_launch(void* const* d_in, const int* in_sizes, int n_in,
                              void* d_out, int out_size, void* d_ws, size_t ws_size,
                              hipStream_t stream) {
    const float* img   = (const float*)d_in[0];
    const float* text  = (const float*)d_in[1];
    const float* Wt    = (const float*)d_in[2];
    const float* gamma = (const float*)d_in[3];
    float* out = (float*)d_out;
    char* ws = (char*)d_ws;
    u16*   tc_bf  = (u16*)(ws);                   // 32*768*96*2 = 4,718,592
    u16*   tlc_bf = (u16*)(ws + 4718592);         // 32*80*768*2 = 3,932,160
    u16*   qh_bf  = (u16*)(ws + 8650752);         // 32*768*96*2 = 4,718,592
    float* u_ws   = (float*)(ws + 13369344);      // 32*768*80*4 = 7,864,320
    u16*   At_bf  = (u16*)(ws + 21233664);        // 2464*512*2  = 2,523,136
    u16*   Wb_bf  = (u16*)(ws + 23756800);        // 768*512*2   =   786,432

    k_cvt_text<<<dim3((MROWS * DD / 4 + 255) / 256), 256, 0, stream>>>(text, At_bf);
    k_cvt_w   <<<dim3(CC / 32, DD / 32), 256, 0, stream>>>(Wt, Wb_bf);
    k_pad     <<<dim3((BB * 3 * CC + 255) / 256), 256, 0, stream>>>(tc_bf, tlc_bf);
    k_tgemm_mfma<<<dim3(MROWS / 16, 4), 256, 0, stream>>>(At_bf, Wb_bf, tc_bf, tlc_bf);
    k_qh  <<<dim3(256, BB), 256, 0, stream>>>(img, qh_bf);
    k_attn<<<dim3(48, BB), 256, 0, stream>>>(qh_bf, tc_bf, tlc_bf, u_ws);
    k_out <<<dim3(CC, BB), 256, 0, stream>>>(img, u_ws, gamma, out);
}